// Round 20
// baseline (152.673 us; speedup 1.0000x reference)
//
#include <hip/hip_runtime.h>
#include <math.h>

// Problem constants: B=2, S=2048, D=1024, H=16, dk=64
#define SB 2            // batch
#define SS 2048         // seq
#define SD 1024         // d_model
#define SH 16           // heads
#define SDK 64          // d_k
#define MROWS (SB*SS)   // 4096

#define L2E 1.44269504088896341f
#define SCL2E (0.125f * L2E)      // (1/sqrt(dk)) * log2(e)
#define M0 8.0f                   // fixed softmax offset (softmax invariant to it)

typedef float  f32x4  __attribute__((ext_vector_type(4)));
typedef float  f32x16 __attribute__((ext_vector_type(16)));
typedef __bf16 bf16x8 __attribute__((ext_vector_type(8)));
typedef short  short8 __attribute__((ext_vector_type(8), may_alias));
typedef short  short4a __attribute__((ext_vector_type(4), may_alias));
typedef float  floatx4a __attribute__((ext_vector_type(4), may_alias));
typedef unsigned uint4v __attribute__((ext_vector_type(4)));

__device__ __forceinline__ short f2bf(float f) {
    unsigned u = __float_as_uint(f);
    u += 0x7fffu + ((u >> 16) & 1u);          // round-to-nearest-even
    return (short)(u >> 16);
}
__device__ __forceinline__ float bf2f(short v) {
    return __uint_as_float(((unsigned)(unsigned short)v) << 16);
}
__device__ __forceinline__ bf16x8 ldb(const short* p) {
    short8 v = *(const short8*)p;
    return __builtin_bit_cast(bf16x8, v);
}
__device__ __forceinline__ unsigned cvtpk(float lo, float hi) {
    unsigned r;
    asm("v_cvt_pk_bf16_f32 %0, %1, %2" : "=v"(r) : "v"(lo), "v"(hi));
    return r;
}
__device__ __forceinline__ void gload16(const short* g, short* l) {
    __builtin_amdgcn_global_load_lds(
        (const __attribute__((address_space(1))) unsigned*)g,
        (__attribute__((address_space(3))) unsigned*)l, 16, 0, 0);
}
#define MFMA(a, b, c)   __builtin_amdgcn_mfma_f32_16x16x32_bf16((a), (b), (c), 0, 0, 0)
#define MFMA32(a, b, c) __builtin_amdgcn_mfma_f32_32x32x16_bf16((a), (b), (c), 0, 0, 0)

// ---------------- fused f32 -> bf16 convert: ONE launch for all 7 tensors ----
__global__ __launch_bounds__(256) void conv_all(
    const float* __restrict__ q, const float* __restrict__ k, const float* __restrict__ v,
    const float* __restrict__ Wq, const float* __restrict__ Wk,
    const float* __restrict__ Wv, const float* __restrict__ Wo,
    short* __restrict__ qb, short* __restrict__ kb, short* __restrict__ vb,
    short* __restrict__ wqb, short* __restrict__ wkb,
    short* __restrict__ wvb, short* __restrict__ wob)
{
    const int y = blockIdx.y;
    const float* src; short* dst; int n;
    switch (y) {
        case 0: src = q;  dst = qb;  n = MROWS * SD; break;
        case 1: src = k;  dst = kb;  n = MROWS * SD; break;
        case 2: src = v;  dst = vb;  n = MROWS * SD; break;
        case 3: src = Wq; dst = wqb; n = SD * SD; break;
        case 4: src = Wk; dst = wkb; n = SD * SD; break;
        case 5: src = Wv; dst = wvb; n = SD * SD; break;
        default: src = Wo; dst = wob; n = SD * SD; break;
    }
    int i = (blockIdx.x * 256 + threadIdx.x) * 4;
    if (i >= n) return;
    floatx4a x = *(const floatx4a*)(src + i);
    short4a o;
    o[0] = f2bf(x[0]); o[1] = f2bf(x[1]); o[2] = f2bf(x[2]); o[3] = f2bf(x[3]);
    *(short4a*)(dst + i) = o;
}

// ---------------- proj GEMM (r12-proven, z=0/1 only): Q,K projections -------
__global__ __launch_bounds__(256) void gemm128(
    const short* __restrict__ X0, const short* __restrict__ X1,
    const short* __restrict__ W0, const short* __restrict__ W1,
    const float* __restrict__ bias0, const float* __restrict__ bias1,
    short* __restrict__ O0, short* __restrict__ O1)
{
    const int z = blockIdx.z;
    const short* X = (z == 0) ? X0 : X1;
    const short* W = (z == 0) ? W0 : W1;
    const float* Bv = (z == 0) ? bias0 : bias1;
    short* Obf = (z == 0) ? O0 : O1;

    const int bm = 4 * blockIdx.x + (blockIdx.y >> 3);   // XCD-clustered rows
    const int bn = blockIdx.y & 7;
    const int tid = threadIdx.x;
    const int w = tid >> 6, lane = tid & 63, g = lane >> 4, r = lane & 15;
    const int wm = w >> 1, wn = w & 1;

    __shared__ short As[128 * 32];
    __shared__ short Bsm[128 * 32];

    const int srow = tid >> 2, sseg = tid & 3;
    const short* ga0 = X + (size_t)(bm * 128 + srow) * SD + sseg * 8;
    const short* ga1 = X + (size_t)(bm * 128 + 64 + srow) * SD + sseg * 8;
    const short* gb0 = W + (size_t)(bn * 128 + srow) * SD + sseg * 8;
    const short* gb1 = W + (size_t)(bn * 128 + 64 + srow) * SD + sseg * 8;
    short* la0 = As + tid * 8;
    short* la1 = As + 2048 + tid * 8;
    short* lb0 = Bsm + tid * 8;
    short* lb1 = Bsm + 2048 + tid * 8;

    f32x4 acc[4][4];
    const f32x4 zz = {0.f, 0.f, 0.f, 0.f};
#pragma unroll
    for (int i = 0; i < 4; i++)
#pragma unroll
        for (int j = 0; j < 4; j++) acc[i][j] = zz;

    for (int kt = 0; kt < 32; ++kt) {
        if (kt) __syncthreads();
        gload16(ga0 + kt * 32, la0);
        gload16(ga1 + kt * 32, la1);
        gload16(gb0 + kt * 32, lb0);
        gload16(gb1 + kt * 32, lb1);
        __syncthreads();
        bf16x8 af[4], bfr[4];
#pragma unroll
        for (int mf = 0; mf < 4; mf++) af[mf] = ldb(&As[(wm * 64 + mf * 16 + r) * 32 + g * 8]);
#pragma unroll
        for (int nf = 0; nf < 4; nf++) bfr[nf] = ldb(&Bsm[(wn * 64 + nf * 16 + r) * 32 + g * 8]);
#pragma unroll
        for (int mf = 0; mf < 4; mf++)
#pragma unroll
            for (int nf = 0; nf < 4; nf++)
                acc[mf][nf] = MFMA(af[mf], bfr[nf], acc[mf][nf]);
    }

    float bv[4];
#pragma unroll
    for (int nf = 0; nf < 4; nf++) bv[nf] = Bv[bn * 128 + wn * 64 + nf * 16 + r];

#pragma unroll
    for (int mf = 0; mf < 4; mf++)
#pragma unroll
        for (int nf = 0; nf < 4; nf++)
#pragma unroll
            for (int rr = 0; rr < 4; rr++) {
                int row = bm * 128 + wm * 64 + mf * 16 + g * 4 + rr;  // m index
                int col = bn * 128 + wn * 64 + nf * 16 + r;           // n index
                float v = acc[mf][nf][rr] + bv[nf];
                int b = row >> 11, s = row & 2047, h = col >> 6, d = col & 63;
                Obf[(((size_t)(b * SH + h)) * SS + s) * SDK + d] = f2bf(v);
            }
}

// ---------------- V^T GEMM: VhT = Wv @ x_v^T + bv, written directly ---------
// C[1024 d_model rows][4096 token cols]; 64x128 tiles -> 512 blocks (2/CU).
// XCD map: all Wv (2MB) + 4 token panels (1MB) per XCD L2. Epilogue stores
// s per-lane (16x2B contiguous) — same coalescing as gemm128's scatter.
__global__ __launch_bounds__(256) void gemm_vt(
    const short* __restrict__ Wv, const short* __restrict__ Xv,
    const float* __restrict__ Bv, short* __restrict__ VhT)
{
    const int i = blockIdx.x;
    const int xcd = i & 7, j = i >> 3;
    const int bm = j >> 2;             // 16 x 64 d_model rows
    const int bn = 4 * xcd + (j & 3);  // 32 x 128 tokens, XCD-clustered
    const int tid = threadIdx.x;
    const int w = tid >> 6, lane = tid & 63, g = lane >> 4, r = lane & 15;
    const int wm = w >> 1, wn = w & 1;

    __shared__ short As[64 * 32];
    __shared__ short Bsm[128 * 32];

    const int srow = tid >> 2, sseg = tid & 3;
    const short* ga0 = Wv + (size_t)(bm * 64 + srow) * SD + sseg * 8;
    const short* gb0 = Xv + (size_t)(bn * 128 + srow) * SD + sseg * 8;
    const short* gb1 = Xv + (size_t)(bn * 128 + 64 + srow) * SD + sseg * 8;
    short* la0 = As + tid * 8;
    short* lb0 = Bsm + tid * 8;
    short* lb1 = Bsm + 2048 + tid * 8;

    f32x4 acc[2][4];
    const f32x4 zz = {0.f, 0.f, 0.f, 0.f};
#pragma unroll
    for (int a = 0; a < 2; a++)
#pragma unroll
        for (int b2 = 0; b2 < 4; b2++) acc[a][b2] = zz;

    for (int kt = 0; kt < 32; ++kt) {
        if (kt) __syncthreads();
        gload16(ga0 + kt * 32, la0);
        gload16(gb0 + kt * 32, lb0);
        gload16(gb1 + kt * 32, lb1);
        __syncthreads();
        bf16x8 af[2], bfr[4];
#pragma unroll
        for (int mf = 0; mf < 2; mf++) af[mf] = ldb(&As[(wm * 32 + mf * 16 + r) * 32 + g * 8]);
#pragma unroll
        for (int nf = 0; nf < 4; nf++) bfr[nf] = ldb(&Bsm[(wn * 64 + nf * 16 + r) * 32 + g * 8]);
#pragma unroll
        for (int mf = 0; mf < 2; mf++)
#pragma unroll
            for (int nf = 0; nf < 4; nf++)
                acc[mf][nf] = MFMA(af[mf], bfr[nf], acc[mf][nf]);
    }

#pragma unroll
    for (int mf = 0; mf < 2; mf++)
#pragma unroll
        for (int nf = 0; nf < 4; nf++)
#pragma unroll
            for (int rr = 0; rr < 4; rr++) {
                int row = bm * 64 + wm * 32 + mf * 16 + g * 4 + rr;   // d_model idx
                int col = bn * 128 + wn * 64 + nf * 16 + r;           // token idx
                int h = row >> 6, d = row & 63, b = col >> 11, s = col & 2047;
                VhT[(((size_t)(b * SH + h)) * SDK + d) * SS + s] =
                    f2bf(acc[mf][nf][rr] + Bv[row]);
            }
}

// ---------------- output GEMM (r13-proven): 128x64 tiles, 512 blocks --------
__global__ __launch_bounds__(256) void gemm_out(
    const short* __restrict__ X, const short* __restrict__ W,
    const float* __restrict__ Bv, float* __restrict__ OutF)
{
    const int i = blockIdx.x;
    const int xcd = i & 7, j = i >> 3;
    const int bm = 4 * xcd + (j & 3);
    const int bn = j >> 2;
    const int tid = threadIdx.x;
    const int w = tid >> 6, lane = tid & 63, g = lane >> 4, r = lane & 15;
    const int wm = w >> 1, wn = w & 1;

    __shared__ short As[128 * 32];
    __shared__ short Bsm[64 * 32];

    const int srow = tid >> 2, sseg = tid & 3;
    const short* ga0 = X + (size_t)(bm * 128 + srow) * SD + sseg * 8;
    const short* ga1 = X + (size_t)(bm * 128 + 64 + srow) * SD + sseg * 8;
    const short* gb0 = W + (size_t)(bn * 64 + srow) * SD + sseg * 8;
    short* la0 = As + tid * 8;
    short* la1 = As + 2048 + tid * 8;
    short* lb0 = Bsm + tid * 8;

    f32x4 acc[4][2];
    const f32x4 zz = {0.f, 0.f, 0.f, 0.f};
#pragma unroll
    for (int a = 0; a < 4; a++) { acc[a][0] = zz; acc[a][1] = zz; }

    for (int kt = 0; kt < 32; ++kt) {
        if (kt) __syncthreads();
        gload16(ga0 + kt * 32, la0);
        gload16(ga1 + kt * 32, la1);
        gload16(gb0 + kt * 32, lb0);
        __syncthreads();
        bf16x8 af[4], bfr[2];
#pragma unroll
        for (int mf = 0; mf < 4; mf++) af[mf] = ldb(&As[(wm * 64 + mf * 16 + r) * 32 + g * 8]);
#pragma unroll
        for (int nf = 0; nf < 2; nf++) bfr[nf] = ldb(&Bsm[(wn * 32 + nf * 16 + r) * 32 + g * 8]);
#pragma unroll
        for (int mf = 0; mf < 4; mf++)
#pragma unroll
            for (int nf = 0; nf < 2; nf++)
                acc[mf][nf] = MFMA(af[mf], bfr[nf], acc[mf][nf]);
    }

    float bv[2];
#pragma unroll
    for (int nf = 0; nf < 2; nf++) bv[nf] = Bv[bn * 64 + wn * 32 + nf * 16 + r];

#pragma unroll
    for (int mf = 0; mf < 4; mf++)
#pragma unroll
        for (int nf = 0; nf < 2; nf++)
#pragma unroll
            for (int rr = 0; rr < 4; rr++) {
                int row = bm * 128 + wm * 64 + mf * 16 + g * 4 + rr;
                int col = bn * 64 + wn * 32 + nf * 16 + r;
                OutF[(size_t)row * SD + col] = acc[mf][nf][rr] + bv[nf];
            }
}

// ---------------- mask -> folded exp2 bias table ----------------
__global__ __launch_bounds__(256) void make_mb2(const int* __restrict__ mask,
                                                float* __restrict__ mb2)
{
    int i = blockIdx.x * 256 + threadIdx.x;
    if (i < SS) mb2[i] = ((mask[i] != 0) ? 0.f : -1.0e9f * L2E) - M0 * L2E;
}

// ---------------- attention v6 + setprio (r13-proven, FROZEN control) -------
__global__ __launch_bounds__(256, 4) void attn_v6(
    const short* __restrict__ Qh, const short* __restrict__ Kh,
    const short* __restrict__ VhT, const float* __restrict__ mb2,
    short* __restrict__ attnb)
{
    const int blk = blockIdx.x;
    const int xcd = blk & 7, j = blk >> 3;
    const int qc = j & 31, bh = xcd + 8 * (j >> 5);
    const int tid = threadIdx.x;
    const int w = tid >> 6, l = tid & 63;
    const int q5 = l & 31, h = l >> 5;
    const int qch = w & 1, kh = w >> 1;
    const int swk = q5 & 7;
    const int swv = (q5 ^ (q5 >> 2)) & 3;
    const int qbase = qc * 64 + qch * 32;
    const int kbase = kh * 1024;

    const short* Qg = Qh + ((size_t)bh * SS + qbase) * SDK;
    const short* Kg = Kh + (size_t)bh * SS * SDK;
    const short* Vt = VhT + (size_t)bh * SDK * SS;   // [64][2048]

    __shared__ short smem[16384];
    short* base = smem;

    bf16x8 qf[4];
#pragma unroll
    for (int t = 0; t < 4; t++)
        qf[t] = ldb(Qg + (size_t)q5 * SDK + t * 16 + h * 8);

    f32x16 oacc0, oacc1;
#pragma unroll
    for (int i = 0; i < 16; i++) { oacc0[i] = 0.f; oacc1[i] = 0.f; }
    float lsum = 0.f;

    const int ptid = tid & 127;
    short8 stK[2], stV[2];

#define STAGE_LOAD(TK)                                                          \
    {                                                                           \
        _Pragma("unroll")                                                       \
        for (int i_ = 0; i_ < 2; i_++) {                                        \
            int c_ = ptid + i_ * 128;                                           \
            int kr_ = c_ >> 3, ks_ = c_ & 7;                                    \
            stK[i_] = *(const short8*)(Kg + (size_t)(kbase + (TK) * 32 + kr_) * SDK + ks_ * 8); \
            int vr_ = c_ >> 2, vs_ = c_ & 3;                                    \
            stV[i_] = *(const short8*)(Vt + (size_t)vr_ * SS + kbase + (TK) * 32 + vs_ * 8);    \
        }                                                                       \
    }
#define STAGE_WRITE(BUF)                                                        \
    {                                                                           \
        short* kp_ = base + ((kh * 2 + (BUF)) * 2 + 0) * 2048;                  \
        short* vp_ = base + ((kh * 2 + (BUF)) * 2 + 1) * 2048;                  \
        _Pragma("unroll")                                                       \
        for (int i_ = 0; i_ < 2; i_++) {                                        \
            int c_ = ptid + i_ * 128;                                           \
            int kr_ = c_ >> 3, ks_ = c_ & 7;                                    \
            *(short8*)&kp_[(kr_ * 8 + (ks_ ^ (kr_ & 7))) * 8] = stK[i_];        \
            int vr_ = c_ >> 2, vs_ = c_ & 3;                                    \
            *(short8*)&vp_[(vr_ * 4 + (vs_ ^ ((vr_ ^ (vr_ >> 2)) & 3))) * 8] = stV[i_]; \
        }                                                                       \
    }
#define LDK(BUF, T) ldb(&base[((kh * 2 + (BUF)) * 2 + 0) * 2048 + (q5 * 8 + (((T) * 2 + h) ^ swk)) * 8])
#define LDV(BUF, G2, T) ldb(&base[((kh * 2 + (BUF)) * 2 + 1) * 2048 + ((q5 + 32 * (G2)) * 4 + (((T) * 2 + h) ^ swv)) * 8])

    STAGE_LOAD(0);
    STAGE_WRITE(0);
    __syncthreads();
    int cur = 0;

    for (int kt = 0; kt < 32; ++kt) {
        if (kt < 31) STAGE_LOAD(kt + 1);

        f32x16 sg0;
#pragma unroll
        for (int i = 0; i < 16; i++) sg0[i] = 0.f;
        __builtin_amdgcn_s_setprio(1);
#pragma unroll
        for (int t = 0; t < 4; t++) {
            bf16x8 kf = LDK(cur, t);
            sg0 = MFMA32(kf, qf[t], sg0);
        }
        __builtin_amdgcn_s_setprio(0);

        const float* mb_ = mb2 + kbase + kt * 32;
#pragma unroll
        for (int a = 0; a < 4; a++) {
            floatx4a m4 = *(const floatx4a*)(mb_ + a * 8 + 4 * h);
#pragma unroll
            for (int b3 = 0; b3 < 4; b3++) {
                float p0 = __builtin_amdgcn_exp2f(fmaf(sg0[a * 4 + b3], SCL2E, m4[b3]));
                sg0[a * 4 + b3] = p0;
                lsum += p0;
            }
        }

        __builtin_amdgcn_s_setprio(1);
#pragma unroll
        for (int t = 0; t < 2; t++) {
            const int b8 = t * 8;
            unsigned u0 = cvtpk(sg0[b8 + 0], sg0[b8 + 1]);
            unsigned u1 = cvtpk(sg0[b8 + 2], sg0[b8 + 3]);
            unsigned u2 = cvtpk(sg0[b8 + 4], sg0[b8 + 5]);
            unsigned u3 = cvtpk(sg0[b8 + 6], sg0[b8 + 7]);
            asm("v_permlane32_swap_b32 %0, %1" : "+v"(u0), "+v"(u2));
            asm("v_permlane32_swap_b32 %0, %1" : "+v"(u1), "+v"(u3));
            uint4v uw = {u0, u1, u2, u3};
            bf16x8 pa = __builtin_bit_cast(bf16x8, uw);
            bf16x8 vf0 = LDV(cur, 0, t);
            bf16x8 vf1 = LDV(cur, 1, t);
            oacc0 = MFMA32(pa, vf0, oacc0);
            oacc1 = MFMA32(pa, vf1, oacc1);
        }
        __builtin_amdgcn_s_setprio(0);

        if (kt < 31) STAGE_WRITE(cur ^ 1);
        __syncthreads();
        cur ^= 1;
    }
#undef STAGE_LOAD
#undef STAGE_WRITE
#undef LDK
#undef LDV

    __syncthreads();
    float* cm = (float*)smem;        // [qch][lane][33]
    if (kh == 1) {
        float* dst = cm + (qch * 64 + l) * 33;
#pragma unroll
        for (int i = 0; i < 16; i++) { dst[i] = oacc0[i]; dst[16 + i] = oacc1[i]; }
        dst[32] = lsum;
    }
    __syncthreads();
    if (kh == 0) {
        const float* src = cm + (qch * 64 + l) * 33;
#pragma unroll
        for (int i = 0; i < 16; i++) { oacc0[i] += src[i]; oacc1[i] += src[16 + i]; }
        lsum += src[32];
        lsum += __shfl_xor(lsum, 32);
        float inv = 1.f / lsum;
        const int b = bh >> 4, hh = bh & 15;
#pragma unroll
        for (int i = 0; i < 16; i++) {
            int qrow = (i & 3) + 8 * (i >> 2) + 4 * h;
            float invq = __shfl(inv, (l & 32) + qrow);
            int qg = qbase + qrow;
            size_t ob = ((size_t)(b * SS + qg)) * SD + hh * SDK;
            attnb[ob + q5]      = f2bf(oacc0[i] * invq);
            attnb[ob + 32 + q5] = f2bf(oacc1[i] * invq);
        }
    }
}

// ---------------- bias path: widened partials + combine ----------------
__global__ __launch_bounds__(256) void bias_part(const short* __restrict__ Qh,
                                                 const short* __restrict__ VhT,
                                                 float* __restrict__ qpart,
                                                 float* __restrict__ vpart)
{
    const int bh = blockIdx.x >> 3, ch = blockIdx.x & 7;
    const int t = threadIdx.x;
    const int d = t & 63, c = t >> 6;
    const short* Qp = Qh + ((size_t)bh * SS + ch * 256 + c * 64) * SDK + d;
    float sq = 0.f;
    for (int s = 0; s < 64; s++) sq += bf2f(Qp[(size_t)s * SDK]);
    const short* Vp = VhT + ((size_t)bh * SDK + (t >> 2)) * SS + ch * 256 + (t & 3) * 64;
    float sv = 0.f;
    for (int s8 = 0; s8 < 8; s8++) {
        short8 v8 = *(const short8*)(Vp + s8 * 8);
#pragma unroll
        for (int jj = 0; jj < 8; jj++) sv += bf2f(v8[jj]);
    }
    __shared__ float SQ[4][64], SV[64][4];
    SQ[c][d] = sq; SV[t >> 2][t & 3] = sv;
    __syncthreads();
    if (t < 64) {
        qpart[((size_t)bh * 8 + ch) * 64 + t] = SQ[0][t] + SQ[1][t] + SQ[2][t] + SQ[3][t];
        vpart[((size_t)bh * 8 + ch) * 64 + t] = SV[t][0] + SV[t][1] + SV[t][2] + SV[t][3];
    }
}

__global__ __launch_bounds__(64) void bias_fin(const float* __restrict__ qpart,
                                               const float* __restrict__ vpart,
                                               float* __restrict__ biasbuf)
{
    const int bh = blockIdx.x;
    const int t = threadIdx.x;
    float qm = 0.f, vm = 0.f;
#pragma unroll
    for (int ch = 0; ch < 8; ch++) {
        qm += qpart[((size_t)bh * 8 + ch) * 64 + t];
        vm += vpart[((size_t)bh * 8 + ch) * 64 + t];
    }
    qm *= (1.f / 2048.f); vm *= (1.f / 2048.f);
    float dot = qm * vm, nq = qm * qm, nv = vm * vm;
#pragma unroll
    for (int m2 = 1; m2 < 64; m2 <<= 1) {
        dot += __shfl_xor(dot, m2);
        nq += __shfl_xor(nq, m2);
        nv += __shfl_xor(nv, m2);
    }
    if (t == 0) {
        float na = fmaxf(sqrtf(nq), 1e-8f);
        float nb = fmaxf(sqrtf(nv), 1e-8f);
        biasbuf[bh] = dot / (na * nb);
    }
}

__global__ __launch_bounds__(64) void bias_mean(const float* __restrict__ biasbuf,
                                                float* __restrict__ out, int idx)
{
    int t = threadIdx.x;
    float v = (t < 32) ? biasbuf[t] : 0.f;
#pragma unroll
    for (int m2 = 1; m2 < 32; m2 <<= 1) v += __shfl_xor(v, m2);
    if (t == 0) out[idx] = v * (1.f / 32.f);
}

// ---------------- launcher ----------------
extern "C" void kernel_launch(void* const* d_in, const int* in_sizes, int n_in,
                              void* d_out, int out_size, void* d_ws, size_t ws_size,
                              hipStream_t stream)
{
    const float* q  = (const float*)d_in[0];
    const float* k  = (const float*)d_in[1];
    const float* v  = (const float*)d_in[2];
    const int* mask = (const int*)d_in[3];
    const float* Wq = (const float*)d_in[4];
    const float* bq = (const float*)d_in[5];
    const float* Wk = (const float*)d_in[6];
    const float* bk = (const float*)d_in[7];
    const float* Wv = (const float*)d_in[8];
    const float* bv = (const float*)d_in[9];
    const float* Wo = (const float*)d_in[10];
    const float* bo = (const float*)d_in[11];
    float* out = (float*)d_out;

    const size_t QKV_B = (size_t)MROWS * SD * sizeof(short);  // 8 MB
    const size_t W_B   = (size_t)SD * SD * sizeof(short);     // 2 MB
    size_t off = 0;
    char* ws = (char*)d_ws;
    auto take = [&](size_t b) { void* p = ws + off; off += (b + 255) & ~(size_t)255; return p; };

    short* qb  = (short*)take(QKV_B);
    short* kb  = (short*)take(QKV_B);
    short* vb  = (short*)take(QKV_B);
    short* wqb = (short*)take(W_B);
    short* wkb = (short*)take(W_B);
    short* wvb = (short*)take(W_B);
    short* wob = (short*)take(W_B);
    short* Qh  = (short*)take(QKV_B);   // (b,h,s,d)
    short* Kh  = (short*)take(QKV_B);
    short* VhT = (short*)take(QKV_B);   // (b,h,d,s) — written directly by gemm_vt
    float* qpart = (float*)take(32 * 8 * 64 * sizeof(float));
    float* vpart = (float*)take(32 * 8 * 64 * sizeof(float));
    float* biasbuf = (float*)take(256);
    short* attnb = qb;        // qb dead after projection GEMM
    float* mb2   = (float*)kb; // kb dead after projection GEMM

    conv_all<<<dim3(4096, 7), 256, 0, stream>>>(q, k, v, Wq, Wk, Wv, Wo,
                                                qb, kb, vb, wqb, wkb, wvb, wob);

    // Q,K projections (z=0/1)
    gemm128<<<dim3(SD / 128, MROWS / 128, 2), 256, 0, stream>>>(
        qb, kb, wqb, wkb, bq, bk, Qh, Kh);

    // V^T projection, written directly in (b,h,d,s)
    gemm_vt<<<512, 256, 0, stream>>>(wvb, vb, bv, VhT);

    make_mb2<<<SS / 256, 256, 0, stream>>>(mask, mb2);

    bias_part<<<32 * 8, 256, 0, stream>>>(Qh, VhT, qpart, vpart);
    bias_fin<<<SB * SH, 64, 0, stream>>>(qpart, vpart, biasbuf);

    attn_v6<<<SB * SH * (SS / 64), 256, 0, stream>>>(Qh, Kh, VhT, mb2, attnb);

    gemm_out<<<512, 256, 0, stream>>>(attnb, wob, bo, out);

    bias_mean<<<1, 64, 0, stream>>>(biasbuf, out, out_size - 1);
}

// Round 21
// 147.789 us; speedup vs baseline: 1.0330x; 1.0330x over previous
//
#include <hip/hip_runtime.h>
#include <math.h>

// Problem constants: B=2, S=2048, D=1024, H=16, dk=64
#define SB 2            // batch
#define SS 2048         // seq
#define SD 1024         // d_model
#define SH 16           // heads
#define SDK 64          // d_k
#define MROWS (SB*SS)   // 4096

#define L2E 1.44269504088896341f
#define SCL2E (0.125f * L2E)      // (1/sqrt(dk)) * log2(e)
#define M0 8.0f                   // fixed softmax offset (softmax invariant to it)

typedef float  f32x4  __attribute__((ext_vector_type(4)));
typedef float  f32x16 __attribute__((ext_vector_type(16)));
typedef __bf16 bf16x8 __attribute__((ext_vector_type(8)));
typedef short  short8 __attribute__((ext_vector_type(8), may_alias));
typedef short  short4a __attribute__((ext_vector_type(4), may_alias));
typedef float  floatx4a __attribute__((ext_vector_type(4), may_alias));
typedef unsigned uint4v __attribute__((ext_vector_type(4)));

__device__ __forceinline__ short f2bf(float f) {
    unsigned u = __float_as_uint(f);
    u += 0x7fffu + ((u >> 16) & 1u);          // round-to-nearest-even
    return (short)(u >> 16);
}
__device__ __forceinline__ float bf2f(short v) {
    return __uint_as_float(((unsigned)(unsigned short)v) << 16);
}
__device__ __forceinline__ bf16x8 ldb(const short* p) {
    short8 v = *(const short8*)p;
    return __builtin_bit_cast(bf16x8, v);
}
__device__ __forceinline__ unsigned cvtpk(float lo, float hi) {
    unsigned r;
    asm("v_cvt_pk_bf16_f32 %0, %1, %2" : "=v"(r) : "v"(lo), "v"(hi));
    return r;
}
__device__ __forceinline__ void gload16(const short* g, short* l) {
    __builtin_amdgcn_global_load_lds(
        (const __attribute__((address_space(1))) unsigned*)g,
        (__attribute__((address_space(3))) unsigned*)l, 16, 0, 0);
}
#define MFMA(a, b, c)   __builtin_amdgcn_mfma_f32_16x16x32_bf16((a), (b), (c), 0, 0, 0)
#define MFMA32(a, b, c) __builtin_amdgcn_mfma_f32_32x32x16_bf16((a), (b), (c), 0, 0, 0)

// ---------------- fused f32 -> bf16 convert: ONE launch for all 7 tensors ----
__global__ __launch_bounds__(256) void conv_all(
    const float* __restrict__ q, const float* __restrict__ k, const float* __restrict__ v,
    const float* __restrict__ Wq, const float* __restrict__ Wk,
    const float* __restrict__ Wv, const float* __restrict__ Wo,
    short* __restrict__ qb, short* __restrict__ kb, short* __restrict__ vb,
    short* __restrict__ wqb, short* __restrict__ wkb,
    short* __restrict__ wvb, short* __restrict__ wob)
{
    const int y = blockIdx.y;
    const float* src; short* dst; int n;
    switch (y) {
        case 0: src = q;  dst = qb;  n = MROWS * SD; break;
        case 1: src = k;  dst = kb;  n = MROWS * SD; break;
        case 2: src = v;  dst = vb;  n = MROWS * SD; break;
        case 3: src = Wq; dst = wqb; n = SD * SD; break;
        case 4: src = Wk; dst = wkb; n = SD * SD; break;
        case 5: src = Wv; dst = wvb; n = SD * SD; break;
        default: src = Wo; dst = wob; n = SD * SD; break;
    }
    int i = (blockIdx.x * 256 + threadIdx.x) * 4;
    if (i >= n) return;
    floatx4a x = *(const floatx4a*)(src + i);
    short4a o;
    o[0] = f2bf(x[0]); o[1] = f2bf(x[1]); o[2] = f2bf(x[2]); o[3] = f2bf(x[3]);
    *(short4a*)(dst + i) = o;
}

// ---------------- proj GEMM (r12-proven): C[4096,1024] = X @ W^T + bias -----
__global__ __launch_bounds__(256) void gemm128(
    const short* __restrict__ X0, const short* __restrict__ X1, const short* __restrict__ X2,
    const short* __restrict__ W0, const short* __restrict__ W1, const short* __restrict__ W2,
    const float* __restrict__ bias0, const float* __restrict__ bias1, const float* __restrict__ bias2,
    short* __restrict__ O0, short* __restrict__ O1, short* __restrict__ O2)
{
    const int z = blockIdx.z;
    const short* X = (z == 0) ? X0 : (z == 1) ? X1 : X2;
    const short* W = (z == 0) ? W0 : (z == 1) ? W1 : W2;
    const float* Bv = (z == 0) ? bias0 : (z == 1) ? bias1 : bias2;
    short* Obf = (z == 0) ? O0 : (z == 1) ? O1 : O2;

    const int bm = 4 * blockIdx.x + (blockIdx.y >> 3);   // XCD-clustered rows
    const int bn = blockIdx.y & 7;
    const int tid = threadIdx.x;
    const int w = tid >> 6, lane = tid & 63, g = lane >> 4, r = lane & 15;
    const int wm = w >> 1, wn = w & 1;

    __shared__ short As[128 * 32];
    __shared__ short Bsm[128 * 32];

    const int srow = tid >> 2, sseg = tid & 3;
    const short* ga0 = X + (size_t)(bm * 128 + srow) * SD + sseg * 8;
    const short* ga1 = X + (size_t)(bm * 128 + 64 + srow) * SD + sseg * 8;
    const short* gb0 = W + (size_t)(bn * 128 + srow) * SD + sseg * 8;
    const short* gb1 = W + (size_t)(bn * 128 + 64 + srow) * SD + sseg * 8;
    short* la0 = As + tid * 8;
    short* la1 = As + 2048 + tid * 8;
    short* lb0 = Bsm + tid * 8;
    short* lb1 = Bsm + 2048 + tid * 8;

    f32x4 acc[4][4];
    const f32x4 zz = {0.f, 0.f, 0.f, 0.f};
#pragma unroll
    for (int i = 0; i < 4; i++)
#pragma unroll
        for (int j = 0; j < 4; j++) acc[i][j] = zz;

    for (int kt = 0; kt < 32; ++kt) {
        if (kt) __syncthreads();
        gload16(ga0 + kt * 32, la0);
        gload16(ga1 + kt * 32, la1);
        gload16(gb0 + kt * 32, lb0);
        gload16(gb1 + kt * 32, lb1);
        __syncthreads();
        bf16x8 af[4], bfr[4];
#pragma unroll
        for (int mf = 0; mf < 4; mf++) af[mf] = ldb(&As[(wm * 64 + mf * 16 + r) * 32 + g * 8]);
#pragma unroll
        for (int nf = 0; nf < 4; nf++) bfr[nf] = ldb(&Bsm[(wn * 64 + nf * 16 + r) * 32 + g * 8]);
#pragma unroll
        for (int mf = 0; mf < 4; mf++)
#pragma unroll
            for (int nf = 0; nf < 4; nf++)
                acc[mf][nf] = MFMA(af[mf], bfr[nf], acc[mf][nf]);
    }

    float bv[4];
#pragma unroll
    for (int nf = 0; nf < 4; nf++) bv[nf] = Bv[bn * 128 + wn * 64 + nf * 16 + r];

#pragma unroll
    for (int mf = 0; mf < 4; mf++)
#pragma unroll
        for (int nf = 0; nf < 4; nf++)
#pragma unroll
            for (int rr = 0; rr < 4; rr++) {
                int row = bm * 128 + wm * 64 + mf * 16 + g * 4 + rr;  // m index
                int col = bn * 128 + wn * 64 + nf * 16 + r;           // n index
                float v = acc[mf][nf][rr] + bv[nf];
                int b = row >> 11, s = row & 2047, h = col >> 6, d = col & 63;
                Obf[(((size_t)(b * SH + h)) * SS + s) * SDK + d] = f2bf(v);
            }
}

// ---------------- output GEMM (r13-proven): 128x64 tiles, 512 blocks --------
__global__ __launch_bounds__(256) void gemm_out(
    const short* __restrict__ X, const short* __restrict__ W,
    const float* __restrict__ Bv, float* __restrict__ OutF)
{
    const int i = blockIdx.x;
    const int xcd = i & 7, j = i >> 3;
    const int bm = 4 * xcd + (j & 3);
    const int bn = j >> 2;
    const int tid = threadIdx.x;
    const int w = tid >> 6, lane = tid & 63, g = lane >> 4, r = lane & 15;
    const int wm = w >> 1, wn = w & 1;

    __shared__ short As[128 * 32];
    __shared__ short Bsm[64 * 32];

    const int srow = tid >> 2, sseg = tid & 3;
    const short* ga0 = X + (size_t)(bm * 128 + srow) * SD + sseg * 8;
    const short* ga1 = X + (size_t)(bm * 128 + 64 + srow) * SD + sseg * 8;
    const short* gb0 = W + (size_t)(bn * 64 + srow) * SD + sseg * 8;
    short* la0 = As + tid * 8;
    short* la1 = As + 2048 + tid * 8;
    short* lb0 = Bsm + tid * 8;

    f32x4 acc[4][2];
    const f32x4 zz = {0.f, 0.f, 0.f, 0.f};
#pragma unroll
    for (int a = 0; a < 4; a++) { acc[a][0] = zz; acc[a][1] = zz; }

    for (int kt = 0; kt < 32; ++kt) {
        if (kt) __syncthreads();
        gload16(ga0 + kt * 32, la0);
        gload16(ga1 + kt * 32, la1);
        gload16(gb0 + kt * 32, lb0);
        __syncthreads();
        bf16x8 af[4], bfr[2];
#pragma unroll
        for (int mf = 0; mf < 4; mf++) af[mf] = ldb(&As[(wm * 64 + mf * 16 + r) * 32 + g * 8]);
#pragma unroll
        for (int nf = 0; nf < 2; nf++) bfr[nf] = ldb(&Bsm[(wn * 32 + nf * 16 + r) * 32 + g * 8]);
#pragma unroll
        for (int mf = 0; mf < 4; mf++)
#pragma unroll
            for (int nf = 0; nf < 2; nf++)
                acc[mf][nf] = MFMA(af[mf], bfr[nf], acc[mf][nf]);
    }

    float bv[2];
#pragma unroll
    for (int nf = 0; nf < 2; nf++) bv[nf] = Bv[bn * 64 + wn * 32 + nf * 16 + r];

#pragma unroll
    for (int mf = 0; mf < 4; mf++)
#pragma unroll
        for (int nf = 0; nf < 2; nf++)
#pragma unroll
            for (int rr = 0; rr < 4; rr++) {
                int row = bm * 128 + wm * 64 + mf * 16 + g * 4 + rr;
                int col = bn * 64 + wn * 32 + nf * 16 + r;
                OutF[(size_t)row * SD + col] = acc[mf][nf][rr] + bv[nf];
            }
}

// ---------------- V transpose: Vh[bh][s][d] -> VhT[bh][d][s] ----------------
__global__ __launch_bounds__(256) void transpose_v(const short* __restrict__ Vh,
                                                   short* __restrict__ VhT)
{
    const int bh = blockIdx.x >> 5, st = blockIdx.x & 31;
    __shared__ short T[64][72];
    const int tid = threadIdx.x;
    const int r = tid >> 2, cseg = tid & 3;
    const short* src = Vh + ((size_t)bh * SS + st * 64 + r) * SDK + cseg * 16;
    *(short8*)&T[r][cseg * 16]     = ((const short8*)src)[0];
    *(short8*)&T[r][cseg * 16 + 8] = ((const short8*)src)[1];
    __syncthreads();
    short8 o0, o1;
#pragma unroll
    for (int j = 0; j < 8; j++) {
        o0[j] = T[cseg * 16 + j][r];
        o1[j] = T[cseg * 16 + 8 + j][r];
    }
    short* dst = VhT + ((size_t)bh * SDK + r) * SS + st * 64 + cseg * 16;
    ((short8*)dst)[0] = o0;
    ((short8*)dst)[1] = o1;
}

// ---------------- mask -> folded exp2 bias table ----------------
__global__ __launch_bounds__(256) void make_mb2(const int* __restrict__ mask,
                                                float* __restrict__ mb2)
{
    int i = blockIdx.x * 256 + threadIdx.x;
    if (i < SS) mb2[i] = ((mask[i] != 0) ? 0.f : -1.0e9f * L2E) - M0 * L2E;
}

// ---------------- attention v6 + setprio (r13-proven) ----------------
__global__ __launch_bounds__(256, 4) void attn_v6(
    const short* __restrict__ Qh, const short* __restrict__ Kh,
    const short* __restrict__ VhT, const float* __restrict__ mb2,
    short* __restrict__ attnb)
{
    const int blk = blockIdx.x;
    const int xcd = blk & 7, j = blk >> 3;
    const int qc = j & 31, bh = xcd + 8 * (j >> 5);
    const int tid = threadIdx.x;
    const int w = tid >> 6, l = tid & 63;
    const int q5 = l & 31, h = l >> 5;
    const int qch = w & 1, kh = w >> 1;
    const int swk = q5 & 7;
    const int swv = (q5 ^ (q5 >> 2)) & 3;
    const int qbase = qc * 64 + qch * 32;
    const int kbase = kh * 1024;

    const short* Qg = Qh + ((size_t)bh * SS + qbase) * SDK;
    const short* Kg = Kh + (size_t)bh * SS * SDK;
    const short* Vt = VhT + (size_t)bh * SDK * SS;   // [64][2048]

    __shared__ short smem[16384];
    short* base = smem;

    bf16x8 qf[4];
#pragma unroll
    for (int t = 0; t < 4; t++)
        qf[t] = ldb(Qg + (size_t)q5 * SDK + t * 16 + h * 8);

    f32x16 oacc0, oacc1;
#pragma unroll
    for (int i = 0; i < 16; i++) { oacc0[i] = 0.f; oacc1[i] = 0.f; }
    float lsum = 0.f;

    const int ptid = tid & 127;
    short8 stK[2], stV[2];

#define STAGE_LOAD(TK)                                                          \
    {                                                                           \
        _Pragma("unroll")                                                       \
        for (int i_ = 0; i_ < 2; i_++) {                                        \
            int c_ = ptid + i_ * 128;                                           \
            int kr_ = c_ >> 3, ks_ = c_ & 7;                                    \
            stK[i_] = *(const short8*)(Kg + (size_t)(kbase + (TK) * 32 + kr_) * SDK + ks_ * 8); \
            int vr_ = c_ >> 2, vs_ = c_ & 3;                                    \
            stV[i_] = *(const short8*)(Vt + (size_t)vr_ * SS + kbase + (TK) * 32 + vs_ * 8);    \
        }                                                                       \
    }
#define STAGE_WRITE(BUF)                                                        \
    {                                                                           \
        short* kp_ = base + ((kh * 2 + (BUF)) * 2 + 0) * 2048;                  \
        short* vp_ = base + ((kh * 2 + (BUF)) * 2 + 1) * 2048;                  \
        _Pragma("unroll")                                                       \
        for (int i_ = 0; i_ < 2; i_++) {                                        \
            int c_ = ptid + i_ * 128;                                           \
            int kr_ = c_ >> 3, ks_ = c_ & 7;                                    \
            *(short8*)&kp_[(kr_ * 8 + (ks_ ^ (kr_ & 7))) * 8] = stK[i_];        \
            int vr_ = c_ >> 2, vs_ = c_ & 3;                                    \
            *(short8*)&vp_[(vr_ * 4 + (vs_ ^ ((vr_ ^ (vr_ >> 2)) & 3))) * 8] = stV[i_]; \
        }                                                                       \
    }
#define LDK(BUF, T) ldb(&base[((kh * 2 + (BUF)) * 2 + 0) * 2048 + (q5 * 8 + (((T) * 2 + h) ^ swk)) * 8])
#define LDV(BUF, G2, T) ldb(&base[((kh * 2 + (BUF)) * 2 + 1) * 2048 + ((q5 + 32 * (G2)) * 4 + (((T) * 2 + h) ^ swv)) * 8])

    STAGE_LOAD(0);
    STAGE_WRITE(0);
    __syncthreads();
    int cur = 0;

    for (int kt = 0; kt < 32; ++kt) {
        if (kt < 31) STAGE_LOAD(kt + 1);

        f32x16 sg0;
#pragma unroll
        for (int i = 0; i < 16; i++) sg0[i] = 0.f;
        __builtin_amdgcn_s_setprio(1);
#pragma unroll
        for (int t = 0; t < 4; t++) {
            bf16x8 kf = LDK(cur, t);
            sg0 = MFMA32(kf, qf[t], sg0);
        }
        __builtin_amdgcn_s_setprio(0);

        const float* mb_ = mb2 + kbase + kt * 32;
#pragma unroll
        for (int a = 0; a < 4; a++) {
            floatx4a m4 = *(const floatx4a*)(mb_ + a * 8 + 4 * h);
#pragma unroll
            for (int b3 = 0; b3 < 4; b3++) {
                float p0 = __builtin_amdgcn_exp2f(fmaf(sg0[a * 4 + b3], SCL2E, m4[b3]));
                sg0[a * 4 + b3] = p0;
                lsum += p0;
            }
        }

        __builtin_amdgcn_s_setprio(1);
#pragma unroll
        for (int t = 0; t < 2; t++) {
            const int b8 = t * 8;
            unsigned u0 = cvtpk(sg0[b8 + 0], sg0[b8 + 1]);
            unsigned u1 = cvtpk(sg0[b8 + 2], sg0[b8 + 3]);
            unsigned u2 = cvtpk(sg0[b8 + 4], sg0[b8 + 5]);
            unsigned u3 = cvtpk(sg0[b8 + 6], sg0[b8 + 7]);
            asm("v_permlane32_swap_b32 %0, %1" : "+v"(u0), "+v"(u2));
            asm("v_permlane32_swap_b32 %0, %1" : "+v"(u1), "+v"(u3));
            uint4v uw = {u0, u1, u2, u3};
            bf16x8 pa = __builtin_bit_cast(bf16x8, uw);
            bf16x8 vf0 = LDV(cur, 0, t);
            bf16x8 vf1 = LDV(cur, 1, t);
            oacc0 = MFMA32(pa, vf0, oacc0);
            oacc1 = MFMA32(pa, vf1, oacc1);
        }
        __builtin_amdgcn_s_setprio(0);

        if (kt < 31) STAGE_WRITE(cur ^ 1);
        __syncthreads();
        cur ^= 1;
    }
#undef STAGE_LOAD
#undef STAGE_WRITE
#undef LDK
#undef LDV

    __syncthreads();
    float* cm = (float*)smem;        // [qch][lane][33]
    if (kh == 1) {
        float* dst = cm + (qch * 64 + l) * 33;
#pragma unroll
        for (int i = 0; i < 16; i++) { dst[i] = oacc0[i]; dst[16 + i] = oacc1[i]; }
        dst[32] = lsum;
    }
    __syncthreads();
    if (kh == 0) {
        const float* src = cm + (qch * 64 + l) * 33;
#pragma unroll
        for (int i = 0; i < 16; i++) { oacc0[i] += src[i]; oacc1[i] += src[16 + i]; }
        lsum += src[32];
        lsum += __shfl_xor(lsum, 32);
        float inv = 1.f / lsum;
        const int b = bh >> 4, hh = bh & 15;
#pragma unroll
        for (int i = 0; i < 16; i++) {
            int qrow = (i & 3) + 8 * (i >> 2) + 4 * h;
            float invq = __shfl(inv, (l & 32) + qrow);
            int qg = qbase + qrow;
            size_t ob = ((size_t)(b * SS + qg)) * SD + hh * SDK;
            attnb[ob + q5]      = f2bf(oacc0[i] * invq);
            attnb[ob + 32 + q5] = f2bf(oacc1[i] * invq);
        }
    }
}

// ---------------- bias path: widened partials + combine ----------------
__global__ __launch_bounds__(256) void bias_part(const short* __restrict__ Qh,
                                                 const short* __restrict__ VhT,
                                                 float* __restrict__ qpart,
                                                 float* __restrict__ vpart)
{
    const int bh = blockIdx.x >> 3, ch = blockIdx.x & 7;
    const int t = threadIdx.x;
    const int d = t & 63, c = t >> 6;
    const short* Qp = Qh + ((size_t)bh * SS + ch * 256 + c * 64) * SDK + d;
    float sq = 0.f;
    for (int s = 0; s < 64; s++) sq += bf2f(Qp[(size_t)s * SDK]);
    const short* Vp = VhT + ((size_t)bh * SDK + (t >> 2)) * SS + ch * 256 + (t & 3) * 64;
    float sv = 0.f;
    for (int s8 = 0; s8 < 8; s8++) {
        short8 v8 = *(const short8*)(Vp + s8 * 8);
#pragma unroll
        for (int jj = 0; jj < 8; jj++) sv += bf2f(v8[jj]);
    }
    __shared__ float SQ[4][64], SV[64][4];
    SQ[c][d] = sq; SV[t >> 2][t & 3] = sv;
    __syncthreads();
    if (t < 64) {
        qpart[((size_t)bh * 8 + ch) * 64 + t] = SQ[0][t] + SQ[1][t] + SQ[2][t] + SQ[3][t];
        vpart[((size_t)bh * 8 + ch) * 64 + t] = SV[t][0] + SV[t][1] + SV[t][2] + SV[t][3];
    }
}

__global__ __launch_bounds__(64) void bias_fin(const float* __restrict__ qpart,
                                               const float* __restrict__ vpart,
                                               float* __restrict__ biasbuf)
{
    const int bh = blockIdx.x;
    const int t = threadIdx.x;
    float qm = 0.f, vm = 0.f;
#pragma unroll
    for (int ch = 0; ch < 8; ch++) {
        qm += qpart[((size_t)bh * 8 + ch) * 64 + t];
        vm += vpart[((size_t)bh * 8 + ch) * 64 + t];
    }
    qm *= (1.f / 2048.f); vm *= (1.f / 2048.f);
    float dot = qm * vm, nq = qm * qm, nv = vm * vm;
#pragma unroll
    for (int m2 = 1; m2 < 64; m2 <<= 1) {
        dot += __shfl_xor(dot, m2);
        nq += __shfl_xor(nq, m2);
        nv += __shfl_xor(nv, m2);
    }
    if (t == 0) {
        float na = fmaxf(sqrtf(nq), 1e-8f);
        float nb = fmaxf(sqrtf(nv), 1e-8f);
        biasbuf[bh] = dot / (na * nb);
    }
}

__global__ __launch_bounds__(64) void bias_mean(const float* __restrict__ biasbuf,
                                                float* __restrict__ out, int idx)
{
    int t = threadIdx.x;
    float v = (t < 32) ? biasbuf[t] : 0.f;
#pragma unroll
    for (int m2 = 1; m2 < 32; m2 <<= 1) v += __shfl_xor(v, m2);
    if (t == 0) out[idx] = v * (1.f / 32.f);
}

// ---------------- launcher ----------------
extern "C" void kernel_launch(void* const* d_in, const int* in_sizes, int n_in,
                              void* d_out, int out_size, void* d_ws, size_t ws_size,
                              hipStream_t stream)
{
    const float* q  = (const float*)d_in[0];
    const float* k  = (const float*)d_in[1];
    const float* v  = (const float*)d_in[2];
    const int* mask = (const int*)d_in[3];
    const float* Wq = (const float*)d_in[4];
    const float* bq = (const float*)d_in[5];
    const float* Wk = (const float*)d_in[6];
    const float* bk = (const float*)d_in[7];
    const float* Wv = (const float*)d_in[8];
    const float* bv = (const float*)d_in[9];
    const float* Wo = (const float*)d_in[10];
    const float* bo = (const float*)d_in[11];
    float* out = (float*)d_out;

    const size_t QKV_B = (size_t)MROWS * SD * sizeof(short);  // 8 MB
    const size_t W_B   = (size_t)SD * SD * sizeof(short);     // 2 MB
    size_t off = 0;
    char* ws = (char*)d_ws;
    auto take = [&](size_t b) { void* p = ws + off; off += (b + 255) & ~(size_t)255; return p; };

    short* qb  = (short*)take(QKV_B);
    short* kb  = (short*)take(QKV_B);
    short* vb  = (short*)take(QKV_B);
    short* wqb = (short*)take(W_B);
    short* wkb = (short*)take(W_B);
    short* wvb = (short*)take(W_B);
    short* wob = (short*)take(W_B);
    short* Qh  = (short*)take(QKV_B);   // (b,h,s,d)
    short* Kh  = (short*)take(QKV_B);
    short* Vh  = (short*)take(QKV_B);
    float* qpart = (float*)take(32 * 8 * 64 * sizeof(float));
    float* vpart = (float*)take(32 * 8 * 64 * sizeof(float));
    float* biasbuf = (float*)take(256);
    short* attnb = qb;        // qb dead after projection GEMM
    short* VhT   = vb;        // vb dead after projection GEMM -> V^T [bh][d][s]
    float* mb2   = (float*)kb; // kb dead after projection GEMM

    conv_all<<<dim3(4096, 7), 256, 0, stream>>>(q, k, v, Wq, Wk, Wv, Wo,
                                                qb, kb, vb, wqb, wkb, wvb, wob);

    gemm128<<<dim3(SD / 128, MROWS / 128, 3), 256, 0, stream>>>(
        qb, kb, vb, wqb, wkb, wvb, bq, bk, bv, Qh, Kh, Vh);

    transpose_v<<<32 * 32, 256, 0, stream>>>(Vh, VhT);
    make_mb2<<<SS / 256, 256, 0, stream>>>(mask, mb2);

    bias_part<<<32 * 8, 256, 0, stream>>>(Qh, VhT, qpart, vpart);
    bias_fin<<<SB * SH, 64, 0, stream>>>(qpart, vpart, biasbuf);

    attn_v6<<<SB * SH * (SS / 64), 256, 0, stream>>>(Qh, Kh, VhT, mb2, attnb);

    gemm_out<<<512, 256, 0, stream>>>(attnb, wob, bo, out);

    bias_mean<<<1, 64, 0, stream>>>(biasbuf, out, out_size - 1);
}

// Round 22
// 140.604 us; speedup vs baseline: 1.0858x; 1.0511x over previous
//
#include <hip/hip_runtime.h>
#include <math.h>

// Problem constants: B=2, S=2048, D=1024, H=16, dk=64
#define SB 2            // batch
#define SS 2048         // seq
#define SD 1024         // d_model
#define SH 16           // heads
#define SDK 64          // d_k
#define MROWS (SB*SS)   // 4096

#define L2E 1.44269504088896341f
#define SCL2E (0.125f * L2E)      // (1/sqrt(dk)) * log2(e)
#define M0 8.0f                   // fixed softmax offset (softmax invariant to it)

typedef float  f32x4  __attribute__((ext_vector_type(4)));
typedef float  f32x16 __attribute__((ext_vector_type(16)));
typedef __bf16 bf16x8 __attribute__((ext_vector_type(8)));
typedef short  short8 __attribute__((ext_vector_type(8), may_alias));
typedef short  short4a __attribute__((ext_vector_type(4), may_alias));
typedef float  floatx4a __attribute__((ext_vector_type(4), may_alias));
typedef unsigned uint4v __attribute__((ext_vector_type(4)));

__device__ __forceinline__ short f2bf(float f) {
    unsigned u = __float_as_uint(f);
    u += 0x7fffu + ((u >> 16) & 1u);          // round-to-nearest-even
    return (short)(u >> 16);
}
__device__ __forceinline__ float bf2f(short v) {
    return __uint_as_float(((unsigned)(unsigned short)v) << 16);
}
__device__ __forceinline__ bf16x8 ldb(const short* p) {
    short8 v = *(const short8*)p;
    return __builtin_bit_cast(bf16x8, v);
}
__device__ __forceinline__ unsigned cvtpk(float lo, float hi) {
    unsigned r;
    asm("v_cvt_pk_bf16_f32 %0, %1, %2" : "=v"(r) : "v"(lo), "v"(hi));
    return r;
}
__device__ __forceinline__ void gload16(const short* g, short* l) {
    __builtin_amdgcn_global_load_lds(
        (const __attribute__((address_space(1))) unsigned*)g,
        (__attribute__((address_space(3))) unsigned*)l, 16, 0, 0);
}
#define MFMA(a, b, c)   __builtin_amdgcn_mfma_f32_16x16x32_bf16((a), (b), (c), 0, 0, 0)
#define MFMA32(a, b, c) __builtin_amdgcn_mfma_f32_32x32x16_bf16((a), (b), (c), 0, 0, 0)

// ---------------- fused f32 -> bf16 convert: ONE launch for all 7 tensors ----
__global__ __launch_bounds__(256) void conv_all(
    const float* __restrict__ q, const float* __restrict__ k, const float* __restrict__ v,
    const float* __restrict__ Wq, const float* __restrict__ Wk,
    const float* __restrict__ Wv, const float* __restrict__ Wo,
    short* __restrict__ qb, short* __restrict__ kb, short* __restrict__ vb,
    short* __restrict__ wqb, short* __restrict__ wkb,
    short* __restrict__ wvb, short* __restrict__ wob)
{
    const int y = blockIdx.y;
    const float* src; short* dst; int n;
    switch (y) {
        case 0: src = q;  dst = qb;  n = MROWS * SD; break;
        case 1: src = k;  dst = kb;  n = MROWS * SD; break;
        case 2: src = v;  dst = vb;  n = MROWS * SD; break;
        case 3: src = Wq; dst = wqb; n = SD * SD; break;
        case 4: src = Wk; dst = wkb; n = SD * SD; break;
        case 5: src = Wv; dst = wvb; n = SD * SD; break;
        default: src = Wo; dst = wob; n = SD * SD; break;
    }
    int i = (blockIdx.x * 256 + threadIdx.x) * 4;
    if (i >= n) return;
    floatx4a x = *(const floatx4a*)(src + i);
    short4a o;
    o[0] = f2bf(x[0]); o[1] = f2bf(x[1]); o[2] = f2bf(x[2]); o[3] = f2bf(x[3]);
    *(short4a*)(dst + i) = o;
}

// ---------------- proj GEMM (r12-proven): C[4096,1024] = X @ W^T + bias -----
__global__ __launch_bounds__(256) void gemm128(
    const short* __restrict__ X0, const short* __restrict__ X1, const short* __restrict__ X2,
    const short* __restrict__ W0, const short* __restrict__ W1, const short* __restrict__ W2,
    const float* __restrict__ bias0, const float* __restrict__ bias1, const float* __restrict__ bias2,
    short* __restrict__ O0, short* __restrict__ O1, short* __restrict__ O2)
{
    const int z = blockIdx.z;
    const short* X = (z == 0) ? X0 : (z == 1) ? X1 : X2;
    const short* W = (z == 0) ? W0 : (z == 1) ? W1 : W2;
    const float* Bv = (z == 0) ? bias0 : (z == 1) ? bias1 : bias2;
    short* Obf = (z == 0) ? O0 : (z == 1) ? O1 : O2;

    const int bm = 4 * blockIdx.x + (blockIdx.y >> 3);   // XCD-clustered rows
    const int bn = blockIdx.y & 7;
    const int tid = threadIdx.x;
    const int w = tid >> 6, lane = tid & 63, g = lane >> 4, r = lane & 15;
    const int wm = w >> 1, wn = w & 1;

    __shared__ short As[128 * 32];
    __shared__ short Bsm[128 * 32];

    const int srow = tid >> 2, sseg = tid & 3;
    const short* ga0 = X + (size_t)(bm * 128 + srow) * SD + sseg * 8;
    const short* ga1 = X + (size_t)(bm * 128 + 64 + srow) * SD + sseg * 8;
    const short* gb0 = W + (size_t)(bn * 128 + srow) * SD + sseg * 8;
    const short* gb1 = W + (size_t)(bn * 128 + 64 + srow) * SD + sseg * 8;
    short* la0 = As + tid * 8;
    short* la1 = As + 2048 + tid * 8;
    short* lb0 = Bsm + tid * 8;
    short* lb1 = Bsm + 2048 + tid * 8;

    f32x4 acc[4][4];
    const f32x4 zz = {0.f, 0.f, 0.f, 0.f};
#pragma unroll
    for (int i = 0; i < 4; i++)
#pragma unroll
        for (int j = 0; j < 4; j++) acc[i][j] = zz;

    for (int kt = 0; kt < 32; ++kt) {
        if (kt) __syncthreads();
        gload16(ga0 + kt * 32, la0);
        gload16(ga1 + kt * 32, la1);
        gload16(gb0 + kt * 32, lb0);
        gload16(gb1 + kt * 32, lb1);
        __syncthreads();
        bf16x8 af[4], bfr[4];
#pragma unroll
        for (int mf = 0; mf < 4; mf++) af[mf] = ldb(&As[(wm * 64 + mf * 16 + r) * 32 + g * 8]);
#pragma unroll
        for (int nf = 0; nf < 4; nf++) bfr[nf] = ldb(&Bsm[(wn * 64 + nf * 16 + r) * 32 + g * 8]);
#pragma unroll
        for (int mf = 0; mf < 4; mf++)
#pragma unroll
            for (int nf = 0; nf < 4; nf++)
                acc[mf][nf] = MFMA(af[mf], bfr[nf], acc[mf][nf]);
    }

    float bv[4];
#pragma unroll
    for (int nf = 0; nf < 4; nf++) bv[nf] = Bv[bn * 128 + wn * 64 + nf * 16 + r];

#pragma unroll
    for (int mf = 0; mf < 4; mf++)
#pragma unroll
        for (int nf = 0; nf < 4; nf++)
#pragma unroll
            for (int rr = 0; rr < 4; rr++) {
                int row = bm * 128 + wm * 64 + mf * 16 + g * 4 + rr;  // m index
                int col = bn * 128 + wn * 64 + nf * 16 + r;           // n index
                float v = acc[mf][nf][rr] + bv[nf];
                int b = row >> 11, s = row & 2047, h = col >> 6, d = col & 63;
                Obf[(((size_t)(b * SH + h)) * SS + s) * SDK + d] = f2bf(v);
            }
}

// ---------------- output GEMM (r13-proven): 128x64 tiles, 512 blocks --------
__global__ __launch_bounds__(256) void gemm_out(
    const short* __restrict__ X, const short* __restrict__ W,
    const float* __restrict__ Bv, float* __restrict__ OutF)
{
    const int i = blockIdx.x;
    const int xcd = i & 7, j = i >> 3;
    const int bm = 4 * xcd + (j & 3);
    const int bn = j >> 2;
    const int tid = threadIdx.x;
    const int w = tid >> 6, lane = tid & 63, g = lane >> 4, r = lane & 15;
    const int wm = w >> 1, wn = w & 1;

    __shared__ short As[128 * 32];
    __shared__ short Bsm[64 * 32];

    const int srow = tid >> 2, sseg = tid & 3;
    const short* ga0 = X + (size_t)(bm * 128 + srow) * SD + sseg * 8;
    const short* ga1 = X + (size_t)(bm * 128 + 64 + srow) * SD + sseg * 8;
    const short* gb0 = W + (size_t)(bn * 64 + srow) * SD + sseg * 8;
    short* la0 = As + tid * 8;
    short* la1 = As + 2048 + tid * 8;
    short* lb0 = Bsm + tid * 8;

    f32x4 acc[4][2];
    const f32x4 zz = {0.f, 0.f, 0.f, 0.f};
#pragma unroll
    for (int a = 0; a < 4; a++) { acc[a][0] = zz; acc[a][1] = zz; }

    for (int kt = 0; kt < 32; ++kt) {
        if (kt) __syncthreads();
        gload16(ga0 + kt * 32, la0);
        gload16(ga1 + kt * 32, la1);
        gload16(gb0 + kt * 32, lb0);
        __syncthreads();
        bf16x8 af[4], bfr[2];
#pragma unroll
        for (int mf = 0; mf < 4; mf++) af[mf] = ldb(&As[(wm * 64 + mf * 16 + r) * 32 + g * 8]);
#pragma unroll
        for (int nf = 0; nf < 2; nf++) bfr[nf] = ldb(&Bsm[(wn * 32 + nf * 16 + r) * 32 + g * 8]);
#pragma unroll
        for (int mf = 0; mf < 4; mf++)
#pragma unroll
            for (int nf = 0; nf < 2; nf++)
                acc[mf][nf] = MFMA(af[mf], bfr[nf], acc[mf][nf]);
    }

    float bv[2];
#pragma unroll
    for (int nf = 0; nf < 2; nf++) bv[nf] = Bv[bn * 64 + wn * 32 + nf * 16 + r];

#pragma unroll
    for (int mf = 0; mf < 4; mf++)
#pragma unroll
        for (int nf = 0; nf < 2; nf++)
#pragma unroll
            for (int rr = 0; rr < 4; rr++) {
                int row = bm * 128 + wm * 64 + mf * 16 + g * 4 + rr;
                int col = bn * 64 + wn * 32 + nf * 16 + r;
                OutF[(size_t)row * SD + col] = acc[mf][nf][rr] + bv[nf];
            }
}

// ---------------- V transpose: Vh[bh][s][d] -> VhT[bh][d][s] ----------------
__global__ __launch_bounds__(256) void transpose_v(const short* __restrict__ Vh,
                                                   short* __restrict__ VhT)
{
    const int bh = blockIdx.x >> 5, st = blockIdx.x & 31;
    __shared__ short T[64][72];
    const int tid = threadIdx.x;
    const int r = tid >> 2, cseg = tid & 3;
    const short* src = Vh + ((size_t)bh * SS + st * 64 + r) * SDK + cseg * 16;
    *(short8*)&T[r][cseg * 16]     = ((const short8*)src)[0];
    *(short8*)&T[r][cseg * 16 + 8] = ((const short8*)src)[1];
    __syncthreads();
    short8 o0, o1;
#pragma unroll
    for (int j = 0; j < 8; j++) {
        o0[j] = T[cseg * 16 + j][r];
        o1[j] = T[cseg * 16 + 8 + j][r];
    }
    short* dst = VhT + ((size_t)bh * SDK + r) * SS + st * 64 + cseg * 16;
    ((short8*)dst)[0] = o0;
    ((short8*)dst)[1] = o1;
}

// ---------------- mask -> folded exp2 bias table ----------------
__global__ __launch_bounds__(256) void make_mb2(const int* __restrict__ mask,
                                                float* __restrict__ mb2)
{
    int i = blockIdx.x * 256 + threadIdx.x;
    if (i < SS) mb2[i] = ((mask[i] != 0) ? 0.f : -1.0e9f * L2E) - M0 * L2E;
}

// ---------------- attention v8: 8 waves = 4 q-chunks x 2 K-halves -----------
// K/V LDS tiles shared by 4 q-chunks (2x less staging traffic/VALU than v6
// for identical compute). Per-wave inner loop identical to v6.
__global__ __launch_bounds__(512, 4) void attn_v8(
    const short* __restrict__ Qh, const short* __restrict__ Kh,
    const short* __restrict__ VhT, const float* __restrict__ mb2,
    short* __restrict__ attnb)
{
    const int blk = blockIdx.x;
    // 512 blocks: 64/XCD clustered on 4 bh (2MB K/V per L2)
    const int xcd = blk & 7, j = blk >> 3;
    const int qc = j & 15, bh = xcd + 8 * (j >> 4);
    const int tid = threadIdx.x;
    const int w = tid >> 6, l = tid & 63;
    const int q5 = l & 31, h = l >> 5;
    const int qch = w & 3, kh = w >> 2;
    const int swk = q5 & 7;
    const int swv = (q5 ^ (q5 >> 2)) & 3;
    const int qbase = qc * 128 + qch * 32;
    const int kbase = kh * 1024;

    const short* Qg = Qh + ((size_t)bh * SS + qbase) * SDK;
    const short* Kg = Kh + (size_t)bh * SS * SDK;
    const short* Vt = VhT + (size_t)bh * SDK * SS;   // [64][2048]

    __shared__ short smem[16384];   // 32 KB: [kh][buf][KV][2048 shorts]
    short* base = smem;

    bf16x8 qf[4];
#pragma unroll
    for (int t = 0; t < 4; t++)
        qf[t] = ldb(Qg + (size_t)q5 * SDK + t * 16 + h * 8);

    f32x16 oacc0, oacc1;
#pragma unroll
    for (int i = 0; i < 16; i++) { oacc0[i] = 0.f; oacc1[i] = 0.f; }
    float lsum = 0.f;

    const int ptid = tid & 255;   // id within kh-group (256 threads stage own half)
    short8 stK, stV;

#define STAGE_LOAD(TK)                                                          \
    {                                                                           \
        int kr_ = ptid >> 3, ks_ = ptid & 7;                                    \
        stK = *(const short8*)(Kg + (size_t)(kbase + (TK) * 32 + kr_) * SDK + ks_ * 8); \
        int vr_ = ptid >> 2, vs_ = ptid & 3;                                    \
        stV = *(const short8*)(Vt + (size_t)vr_ * SS + kbase + (TK) * 32 + vs_ * 8);    \
    }
#define STAGE_WRITE(BUF)                                                        \
    {                                                                           \
        short* kp_ = base + ((kh * 2 + (BUF)) * 2 + 0) * 2048;                  \
        short* vp_ = base + ((kh * 2 + (BUF)) * 2 + 1) * 2048;                  \
        int kr_ = ptid >> 3, ks_ = ptid & 7;                                    \
        *(short8*)&kp_[(kr_ * 8 + (ks_ ^ (kr_ & 7))) * 8] = stK;                \
        int vr_ = ptid >> 2, vs_ = ptid & 3;                                    \
        *(short8*)&vp_[(vr_ * 4 + (vs_ ^ ((vr_ ^ (vr_ >> 2)) & 3))) * 8] = stV; \
    }
#define LDK(BUF, T) ldb(&base[((kh * 2 + (BUF)) * 2 + 0) * 2048 + (q5 * 8 + (((T) * 2 + h) ^ swk)) * 8])
#define LDV(BUF, G2, T) ldb(&base[((kh * 2 + (BUF)) * 2 + 1) * 2048 + ((q5 + 32 * (G2)) * 4 + (((T) * 2 + h) ^ swv)) * 8])

    STAGE_LOAD(0);
    STAGE_WRITE(0);
    __syncthreads();
    int cur = 0;

    for (int kt = 0; kt < 32; ++kt) {
        if (kt < 31) STAGE_LOAD(kt + 1);

        f32x16 sg0;
#pragma unroll
        for (int i = 0; i < 16; i++) sg0[i] = 0.f;
        __builtin_amdgcn_s_setprio(1);
#pragma unroll
        for (int t = 0; t < 4; t++) {
            bf16x8 kf = LDK(cur, t);
            sg0 = MFMA32(kf, qf[t], sg0);
        }
        __builtin_amdgcn_s_setprio(0);

        const float* mb_ = mb2 + kbase + kt * 32;
#pragma unroll
        for (int a = 0; a < 4; a++) {
            floatx4a m4 = *(const floatx4a*)(mb_ + a * 8 + 4 * h);
#pragma unroll
            for (int b3 = 0; b3 < 4; b3++) {
                float p0 = __builtin_amdgcn_exp2f(fmaf(sg0[a * 4 + b3], SCL2E, m4[b3]));
                sg0[a * 4 + b3] = p0;
                lsum += p0;
            }
        }

        __builtin_amdgcn_s_setprio(1);
#pragma unroll
        for (int t = 0; t < 2; t++) {
            const int b8 = t * 8;
            unsigned u0 = cvtpk(sg0[b8 + 0], sg0[b8 + 1]);
            unsigned u1 = cvtpk(sg0[b8 + 2], sg0[b8 + 3]);
            unsigned u2 = cvtpk(sg0[b8 + 4], sg0[b8 + 5]);
            unsigned u3 = cvtpk(sg0[b8 + 6], sg0[b8 + 7]);
            asm("v_permlane32_swap_b32 %0, %1" : "+v"(u0), "+v"(u2));
            asm("v_permlane32_swap_b32 %0, %1" : "+v"(u1), "+v"(u3));
            uint4v uw = {u0, u1, u2, u3};
            bf16x8 pa = __builtin_bit_cast(bf16x8, uw);
            bf16x8 vf0 = LDV(cur, 0, t);
            bf16x8 vf1 = LDV(cur, 1, t);
            oacc0 = MFMA32(pa, vf0, oacc0);
            oacc1 = MFMA32(pa, vf1, oacc1);
        }
        __builtin_amdgcn_s_setprio(0);

        if (kt < 31) STAGE_WRITE(cur ^ 1);
        __syncthreads();
        cur ^= 1;
    }
#undef STAGE_LOAD
#undef STAGE_WRITE
#undef LDK
#undef LDV

    // ---- split-K combine (linear): cm = [qch][lane][32] = 32 KB exactly ----
    __syncthreads();                 // staging area dead; safe to reuse
    float* cm = (float*)smem;
    if (kh == 1) {
        float* dst = cm + (qch * 64 + l) * 32;
#pragma unroll
        for (int i = 0; i < 16; i++) { dst[i] = oacc0[i]; dst[16 + i] = oacc1[i]; }
    }
    __syncthreads();
    if (kh == 0) {
        const float* src = cm + (qch * 64 + l) * 32;
#pragma unroll
        for (int i = 0; i < 16; i++) { oacc0[i] += src[i]; oacc1[i] += src[16 + i]; }
    }
    __syncthreads();
    {   // lsum exchange through first 2 KB (reuse after barrier)
        float* ls = cm;              // [kh][qch][64]
        ls[(kh * 4 + qch) * 64 + l] = lsum;
    }
    __syncthreads();
    if (kh == 0) {
        lsum += cm[(4 + qch) * 64 + l];
        lsum += __shfl_xor(lsum, 32);
        float inv = 1.f / lsum;
        const int b = bh >> 4, hh = bh & 15;
#pragma unroll
        for (int i = 0; i < 16; i++) {
            int qrow = (i & 3) + 8 * (i >> 2) + 4 * h;
            float invq = __shfl(inv, (l & 32) + qrow);
            int qg = qbase + qrow;
            size_t ob = ((size_t)(b * SS + qg)) * SD + hh * SDK;
            attnb[ob + q5]      = f2bf(oacc0[i] * invq);
            attnb[ob + 32 + q5] = f2bf(oacc1[i] * invq);
        }
    }
}

// ---------------- bias path: widened partials + combine ----------------
__global__ __launch_bounds__(256) void bias_part(const short* __restrict__ Qh,
                                                 const short* __restrict__ VhT,
                                                 float* __restrict__ qpart,
                                                 float* __restrict__ vpart)
{
    const int bh = blockIdx.x >> 3, ch = blockIdx.x & 7;
    const int t = threadIdx.x;
    const int d = t & 63, c = t >> 6;
    const short* Qp = Qh + ((size_t)bh * SS + ch * 256 + c * 64) * SDK + d;
    float sq = 0.f;
    for (int s = 0; s < 64; s++) sq += bf2f(Qp[(size_t)s * SDK]);
    const short* Vp = VhT + ((size_t)bh * SDK + (t >> 2)) * SS + ch * 256 + (t & 3) * 64;
    float sv = 0.f;
    for (int s8 = 0; s8 < 8; s8++) {
        short8 v8 = *(const short8*)(Vp + s8 * 8);
#pragma unroll
        for (int jj = 0; jj < 8; jj++) sv += bf2f(v8[jj]);
    }
    __shared__ float SQ[4][64], SV[64][4];
    SQ[c][d] = sq; SV[t >> 2][t & 3] = sv;
    __syncthreads();
    if (t < 64) {
        qpart[((size_t)bh * 8 + ch) * 64 + t] = SQ[0][t] + SQ[1][t] + SQ[2][t] + SQ[3][t];
        vpart[((size_t)bh * 8 + ch) * 64 + t] = SV[t][0] + SV[t][1] + SV[t][2] + SV[t][3];
    }
}

__global__ __launch_bounds__(64) void bias_fin(const float* __restrict__ qpart,
                                               const float* __restrict__ vpart,
                                               float* __restrict__ biasbuf)
{
    const int bh = blockIdx.x;
    const int t = threadIdx.x;
    float qm = 0.f, vm = 0.f;
#pragma unroll
    for (int ch = 0; ch < 8; ch++) {
        qm += qpart[((size_t)bh * 8 + ch) * 64 + t];
        vm += vpart[((size_t)bh * 8 + ch) * 64 + t];
    }
    qm *= (1.f / 2048.f); vm *= (1.f / 2048.f);
    float dot = qm * vm, nq = qm * qm, nv = vm * vm;
#pragma unroll
    for (int m2 = 1; m2 < 64; m2 <<= 1) {
        dot += __shfl_xor(dot, m2);
        nq += __shfl_xor(nq, m2);
        nv += __shfl_xor(nv, m2);
    }
    if (t == 0) {
        float na = fmaxf(sqrtf(nq), 1e-8f);
        float nb = fmaxf(sqrtf(nv), 1e-8f);
        biasbuf[bh] = dot / (na * nb);
    }
}

__global__ __launch_bounds__(64) void bias_mean(const float* __restrict__ biasbuf,
                                                float* __restrict__ out, int idx)
{
    int t = threadIdx.x;
    float v = (t < 32) ? biasbuf[t] : 0.f;
#pragma unroll
    for (int m2 = 1; m2 < 32; m2 <<= 1) v += __shfl_xor(v, m2);
    if (t == 0) out[idx] = v * (1.f / 32.f);
}

// ---------------- launcher ----------------
extern "C" void kernel_launch(void* const* d_in, const int* in_sizes, int n_in,
                              void* d_out, int out_size, void* d_ws, size_t ws_size,
                              hipStream_t stream)
{
    const float* q  = (const float*)d_in[0];
    const float* k  = (const float*)d_in[1];
    const float* v  = (const float*)d_in[2];
    const int* mask = (const int*)d_in[3];
    const float* Wq = (const float*)d_in[4];
    const float* bq = (const float*)d_in[5];
    const float* Wk = (const float*)d_in[6];
    const float* bk = (const float*)d_in[7];
    const float* Wv = (const float*)d_in[8];
    const float* bv = (const float*)d_in[9];
    const float* Wo = (const float*)d_in[10];
    const float* bo = (const float*)d_in[11];
    float* out = (float*)d_out;

    const size_t QKV_B = (size_t)MROWS * SD * sizeof(short);  // 8 MB
    const size_t W_B   = (size_t)SD * SD * sizeof(short);     // 2 MB
    size_t off = 0;
    char* ws = (char*)d_ws;
    auto take = [&](size_t b) { void* p = ws + off; off += (b + 255) & ~(size_t)255; return p; };

    short* qb  = (short*)take(QKV_B);
    short* kb  = (short*)take(QKV_B);
    short* vb  = (short*)take(QKV_B);
    short* wqb = (short*)take(W_B);
    short* wkb = (short*)take(W_B);
    short* wvb = (short*)take(W_B);
    short* wob = (short*)take(W_B);
    short* Qh  = (short*)take(QKV_B);   // (b,h,s,d)
    short* Kh  = (short*)take(QKV_B);
    short* Vh  = (short*)take(QKV_B);
    float* qpart = (float*)take(32 * 8 * 64 * sizeof(float));
    float* vpart = (float*)take(32 * 8 * 64 * sizeof(float));
    float* biasbuf = (float*)take(256);
    short* attnb = qb;        // qb dead after projection GEMM
    short* VhT   = vb;        // vb dead after projection GEMM -> V^T [bh][d][s]
    float* mb2   = (float*)kb; // kb dead after projection GEMM

    conv_all<<<dim3(4096, 7), 256, 0, stream>>>(q, k, v, Wq, Wk, Wv, Wo,
                                                qb, kb, vb, wqb, wkb, wvb, wob);

    gemm128<<<dim3(SD / 128, MROWS / 128, 3), 256, 0, stream>>>(
        qb, kb, vb, wqb, wkb, wvb, bq, bk, bv, Qh, Kh, Vh);

    transpose_v<<<32 * 32, 256, 0, stream>>>(Vh, VhT);
    make_mb2<<<SS / 256, 256, 0, stream>>>(mask, mb2);

    bias_part<<<32 * 8, 256, 0, stream>>>(Qh, VhT, qpart, vpart);
    bias_fin<<<SB * SH, 64, 0, stream>>>(qpart, vpart, biasbuf);

    attn_v8<<<SB * SH * (SS / 128), 512, 0, stream>>>(Qh, Kh, VhT, mb2, attnb);

    gemm_out<<<512, 256, 0, stream>>>(attnb, wob, bo, out);

    bias_mean<<<1, 64, 0, stream>>>(biasbuf, out, out_size - 1);
}